// Round 7
// baseline (808.780 us; speedup 1.0000x reference)
//
#include <hip/hip_runtime.h>
#include <stdint.h>
#include <math.h>

#define NN 50000          // nodes
#define NE 800000         // edges
#define NH 4              // heads

typedef __attribute__((ext_vector_type(8))) short short8;
typedef __attribute__((ext_vector_type(4))) float floatx4;

// ======================= bf16 helpers =======================
__device__ inline float bf2f(uint32_t u16)
{
    return __uint_as_float(u16 << 16);
}
__device__ inline uint16_t f2bf(float f)
{
    uint32_t u = __float_as_uint(f);
    uint32_t r = (u + 0x7fffu + ((u >> 16) & 1u)) >> 16;   // RNE
    return (uint16_t)r;
}
// 2-op unpack of a packed bf16x2 word
__device__ inline void unpk2(uint32_t w, float& lo, float& hi)
{
    lo = __uint_as_float(w << 16);
    hi = __uint_as_float(w & 0xffff0000u);
}
__device__ inline void unpk8(uint4 u, float* f)
{
    unpk2(u.x, f[0], f[1]);
    unpk2(u.y, f[2], f[3]);
    unpk2(u.z, f[4], f[5]);
    unpk2(u.w, f[6], f[7]);
}

// packed bf16x2 dot with f32 accumulate: s += a.lo*b.lo + a.hi*b.hi
__device__ inline void dot2bf(float& s, uint32_t a, uint32_t b)
{
    asm("v_dot2_f32_bf16 %0, %1, %2, %0" : "+v"(s) : "v"(a), "v"(b));
}

// intra-wave LDS producer->consumer sync (single wave; no __syncthreads needed)
__device__ inline void wave_lds_sync()
{
    __builtin_amdgcn_wave_barrier();
    asm volatile("s_waitcnt lgkmcnt(0)" ::: "memory");
    __builtin_amdgcn_wave_barrier();
}

// ======================= JAX threefry2x32 (partitionable mode) =======================
__host__ __device__ inline void tf2x32(uint32_t k0, uint32_t k1,
                                       uint32_t x0, uint32_t x1,
                                       uint32_t& o0, uint32_t& o1)
{
    uint32_t ks2 = k0 ^ k1 ^ 0x1BD11BDAu;
    x0 += k0; x1 += k1;
#define TF_R(r) { x0 += x1; x1 = (x1 << (r)) | (x1 >> (32 - (r))); x1 ^= x0; }
    TF_R(13) TF_R(15) TF_R(26) TF_R(6)
    x0 += k1;  x1 += ks2 + 1u;
    TF_R(17) TF_R(29) TF_R(16) TF_R(24)
    x0 += ks2; x1 += k0 + 2u;
    TF_R(13) TF_R(15) TF_R(26) TF_R(6)
    x0 += k0;  x1 += k1 + 3u;
    TF_R(17) TF_R(29) TF_R(16) TF_R(24)
    x0 += k1;  x1 += ks2 + 4u;
    TF_R(13) TF_R(15) TF_R(26) TF_R(6)
    x0 += ks2; x1 += k0 + 5u;
#undef TF_R
    o0 = x0; o1 = x1;
}

__device__ inline uint32_t jax_bits32(uint32_t k0, uint32_t k1, uint32_t idx)
{
    uint32_t a, b;
    tf2x32(k0, k1, 0u, idx, a, b);
    return a ^ b;
}

__device__ inline float jax_u01(uint32_t bits)
{
    return __uint_as_float((bits >> 9) | 0x3f800000u) - 1.0f;
}

// XLA ErfInv32 (Giles 2012)
__device__ inline float erfinv_f(float x)
{
    float w = -log1pf(-x * x);
    float p;
    if (w < 5.0f) {
        w = w - 2.5f;
        p = 2.81022636e-08f;
        p = fmaf(p, w, 3.43273939e-07f);
        p = fmaf(p, w, -3.5233877e-06f);
        p = fmaf(p, w, -4.39150654e-06f);
        p = fmaf(p, w, 0.00021858087f);
        p = fmaf(p, w, -0.00125372503f);
        p = fmaf(p, w, -0.00417768164f);
        p = fmaf(p, w, 0.246640727f);
        p = fmaf(p, w, 1.50140941f);
    } else {
        w = sqrtf(w) - 3.0f;
        p = -0.000200214257f;
        p = fmaf(p, w, 0.000100950558f);
        p = fmaf(p, w, 0.00134934322f);
        p = fmaf(p, w, -0.00367342844f);
        p = fmaf(p, w, 0.00573950773f);
        p = fmaf(p, w, -0.0076224613f);
        p = fmaf(p, w, 0.00943887047f);
        p = fmaf(p, w, 1.00167406f);
        p = fmaf(p, w, 2.83297682f);
    }
    return p * x;
}

// ======================= utility kernels =======================
__global__ __launch_bounds__(256) void fill_u32_k(uint32_t* p, uint32_t v, int n)
{
    int i = blockIdx.x * blockDim.x + threadIdx.x;
    if (i < n) p[i] = v;
}

// ======================= weight convert: fp32 [B][K][C] -> bf16 Wt [B*C][K] =======================
struct WSeg { const float* src; int B, K, C, off; };
struct WSegs { WSeg s[18]; };

__global__ __launch_bounds__(256) void wconv_k(WSegs segs, uint16_t* __restrict__ Wt)
{
    WSeg sg = segs.s[blockIdx.y];
    int n = sg.B * sg.K * sg.C;
    int i = blockIdx.x * 256 + threadIdx.x;
    if (i >= n) return;
    int kc = sg.K * sg.C;
    int b = i / kc;
    int rr = i - b * kc;
    int k = rr / sg.C;
    int c = rr - k * sg.C;
    Wt[(size_t)sg.off + (size_t)(b * sg.C + c) * sg.K + k] = f2bf(sg.src[i]);
}

// ======================= CSR build (once per launch) =======================
__global__ __launch_bounds__(256) void hist_k(const int* __restrict__ dst, int* __restrict__ deg)
{
    int e = blockIdx.x * blockDim.x + threadIdx.x;
    if (e < NE) atomicAdd(&deg[dst[e]], 1);
}

#define SCAN_CHUNK 1024
#define SCAN_NBLK  ((NN + SCAN_CHUNK - 1) / SCAN_CHUNK)   // 49

__global__ __launch_bounds__(256) void scan1_k(const int* __restrict__ deg,
                                               int* __restrict__ rowptr,
                                               int* __restrict__ bsums)
{
    __shared__ int lds[256];
    int b = blockIdx.x, t = threadIdx.x;
    int base = b * SCAN_CHUNK + t * 4;
    int v0 = (base + 0 < NN) ? deg[base + 0] : 0;
    int v1 = (base + 1 < NN) ? deg[base + 1] : 0;
    int v2 = (base + 2 < NN) ? deg[base + 2] : 0;
    int v3 = (base + 3 < NN) ? deg[base + 3] : 0;
    int s = v0 + v1 + v2 + v3;
    lds[t] = s;
    __syncthreads();
    for (int off = 1; off < 256; off <<= 1) {
        int x = (t >= off) ? lds[t - off] : 0;
        __syncthreads();
        lds[t] += x;
        __syncthreads();
    }
    int excl = lds[t] - s;
    if (base + 0 < NN) rowptr[base + 0] = excl;
    if (base + 1 < NN) rowptr[base + 1] = excl + v0;
    if (base + 2 < NN) rowptr[base + 2] = excl + v0 + v1;
    if (base + 3 < NN) rowptr[base + 3] = excl + v0 + v1 + v2;
    if (t == 255) bsums[b] = lds[255];
}

__global__ void scan2_k(int* bsums)
{
    if (threadIdx.x == 0 && blockIdx.x == 0) {
        int run = 0;
        for (int i = 0; i < SCAN_NBLK; i++) { int t = bsums[i]; bsums[i] = run; run += t; }
    }
}

__global__ __launch_bounds__(256) void scan3_k(int* __restrict__ rowptr,
                                               const int* __restrict__ bsums,
                                               int* __restrict__ cursor)
{
    int i = blockIdx.x * blockDim.x + threadIdx.x;
    if (i < NN) {
        int r = rowptr[i] + bsums[i / SCAN_CHUNK];
        rowptr[i] = r;
        cursor[i] = r;
    }
    if (i == 0) rowptr[NN] = NE;
}

__global__ __launch_bounds__(256) void csr_scatter_k(const int* __restrict__ src,
                                                     const int* __restrict__ dst,
                                                     int* __restrict__ cursor,
                                                     int* __restrict__ esrc)
{
    int e = blockIdx.x * blockDim.x + threadIdx.x;
    if (e >= NE) return;
    int d = dst[e];
    int pos = atomicAdd(&cursor[d], 1);
    esrc[pos] = src[e];
}

// ======================= bf16 MFMA GEMM (feat qkv GEMM; 3-way N-split via blockIdx.y) =========
// Each blockIdx.y handles `ncols` output columns (its own W/C slice); `Ntot` is the C row
// stride. CH=64 doubles MFMA per staging round vs CH=32 at ~the same stage latency, and the
// N-split gives 3 residency rounds so inter-block pipelining covers the chunk-chain latency.
struct GArg { const void* A; const uint16_t* W; uint16_t* C; };
struct GArg3 { GArg a[3]; };

template<int K, int CH, bool AF32>
__global__ __launch_bounds__(256) void gemm_mfma_k(GArg3 gs, int Ntot, int ncols, int relu)
{
    constexpr int KP = K + 8;
    constexpr int KC = K / 8;
    constexpr int NT = CH / 16;
    constexpr int CHP = CH + 8;          // epilogue scratch row pitch
    constexpr int NIT = (2 * CH) / 64;   // store iterations per lane
    static_assert(64 * CHP <= CH * KP, "epilogue scratch must fit in Ws");
    extern __shared__ uint16_t smem[];
    uint16_t* As = smem;             // 64 x KP
    uint16_t* Ws = smem + 64 * KP;   // CH x KP (doubles as epilogue scratch)

    const GArg g = gs.a[blockIdx.y];
    const uint16_t* W = g.W;
    uint16_t* C = g.C;

    const int tid = threadIdx.x;
    const int row0 = blockIdx.x * 64;
    const int w  = tid >> 6;
    const int l  = tid & 63;
    const int lm = l & 15;
    const int lq = l >> 4;

    for (int i = tid; i < 64 * KC; i += 256) {
        int r = i / KC, c = i - r * KC;
        int gr = row0 + r; if (gr >= NN) gr = NN - 1;
        if constexpr (AF32) {
            const float* Af = (const float*)g.A + (size_t)gr * K + c * 8;
            float4 f0 = *(const float4*)Af;
            float4 f1 = *(const float4*)(Af + 4);
            uint4 vv;
            vv.x = (uint32_t)f2bf(f0.x) | ((uint32_t)f2bf(f0.y) << 16);
            vv.y = (uint32_t)f2bf(f0.z) | ((uint32_t)f2bf(f0.w) << 16);
            vv.z = (uint32_t)f2bf(f1.x) | ((uint32_t)f2bf(f1.y) << 16);
            vv.w = (uint32_t)f2bf(f1.z) | ((uint32_t)f2bf(f1.w) << 16);
            *(uint4*)(As + r * KP + c * 8) = vv;
        } else {
            uint4 vv = *(const uint4*)((const uint16_t*)g.A + (size_t)gr * K + c * 8);
            *(uint4*)(As + r * KP + c * 8) = vv;
        }
    }

    const uint16_t* a_base = As + (16 * w + lm) * KP + lq * 8;
    const uint16_t* b_base = Ws + lm * KP + lq * 8;
    uint16_t* sc = Ws + w * 16 * CHP;

    const int nchunks = ncols / CH;
    for (int ch = 0; ch < nchunks; ch++) {
        __syncthreads();
        for (int i = tid; i < CH * KC; i += 256) {
            int r = i / KC, c = i - r * KC;
            uint4 vv = *(const uint4*)(W + (size_t)(ch * CH + r) * K + c * 8);
            *(uint4*)(Ws + r * KP + c * 8) = vv;
        }
        __syncthreads();

        floatx4 acc[NT];
#pragma unroll
        for (int nt = 0; nt < NT; nt++) acc[nt] = (floatx4){0.f, 0.f, 0.f, 0.f};

#pragma unroll
        for (int ks = 0; ks < K / 32; ks++) {
            short8 av = *(const short8*)(a_base + ks * 32);
#pragma unroll
            for (int nt = 0; nt < NT; nt++) {
                short8 bv = *(const short8*)(b_base + nt * 16 * KP + ks * 32);
                acc[nt] = __builtin_amdgcn_mfma_f32_16x16x32_bf16(av, bv, acc[nt], 0, 0, 0);
            }
        }

        __syncthreads();   // Ws reads done -> reuse as scratch

#pragma unroll
        for (int nt = 0; nt < NT; nt++) {
#pragma unroll
            for (int r = 0; r < 4; r++) {
                float v = acc[nt][r];
                if (relu) v = fmaxf(v, 0.0f);
                sc[(lq * 4 + r) * CHP + nt * 16 + lm] = f2bf(v);
            }
        }
        wave_lds_sync();

        constexpr int GPR = CH / 8;
#pragma unroll
        for (int it = 0; it < NIT; it++) {
            int i = l + it * 64;
            int rr = i / GPR, cc = (i - rr * GPR) * 8;
            int gr = row0 + 16 * w + rr;
            if (gr < NN) {
                uint4 vv = *(const uint4*)(sc + rr * CHP + cc);
                *(uint4*)(C + (size_t)gr * Ntot + ch * CH + cc) = vv;
            }
        }
    }
}

// ======================= fused GEMM pair: C2 = op(A @ W1) @ W2 =======================
struct F2Arg { const uint16_t* A; const uint16_t* W1; const uint16_t* W2; uint16_t* C; };
struct F2Args2 { F2Arg a[2]; };

template<int K1, int MODE>
__global__ __launch_bounds__(256) void fused2_k(F2Args2 fs, int Ntot2, uint32_t k0, uint32_t k1)
{
    constexpr int N1 = K1;
    constexpr int CH = 64;
    constexpr int KP = K1 + 8;
    constexpr int KC = K1 / 8;
    constexpr int NC1 = N1 / CH;     // 2 (K1=128) or 1 (K1=64)
    constexpr int NT = CH / 16;      // 4
    constexpr int CHP = CH + 8;
    extern __shared__ uint16_t smem[];
    uint16_t* As = smem;             // 64 x KP (A tile; reused as store scratch in GEMM2)
    uint16_t* Xs = As + 64 * KP;     // 64 x KP (intermediate tile)
    uint16_t* Ws = Xs + 64 * KP;     // CH x KP (weight staging, shared by both GEMMs)

    const F2Arg g = fs.a[blockIdx.y];
    const int tid = threadIdx.x;
    const int row0 = blockIdx.x * 64;
    const int w  = tid >> 6;
    const int l  = tid & 63;
    const int lm = l & 15;
    const int lq = l >> 4;

    // ---- stage A (64 x K1) ----
    for (int i = tid; i < 64 * KC; i += 256) {
        int r = i / KC, c = i - r * KC;
        int gr = row0 + r; if (gr >= NN) gr = NN - 1;
        *(uint4*)(As + r * KP + c * 8) = *(const uint4*)(g.A + (size_t)gr * K1 + c * 8);
    }

    const uint16_t* a_base = As + (16 * w + lm) * KP + lq * 8;
    const uint16_t* b_base = Ws + lm * KP + lq * 8;

    // ---- GEMM1: acc over all N1 columns, held in registers across chunks ----
    floatx4 acc1[NC1][NT];
#pragma unroll
    for (int ch = 0; ch < NC1; ch++)
#pragma unroll
        for (int nt = 0; nt < NT; nt++) acc1[ch][nt] = (floatx4){0.f, 0.f, 0.f, 0.f};

#pragma unroll
    for (int ch = 0; ch < NC1; ch++) {
        __syncthreads();   // A staged (ch 0) / previous chunk's Ws reads done
        for (int i = tid; i < CH * KC; i += 256) {
            int r = i / KC, c = i - r * KC;
            *(uint4*)(Ws + r * KP + c * 8) =
                *(const uint4*)(g.W1 + (size_t)(ch * CH + r) * K1 + c * 8);
        }
        __syncthreads();
#pragma unroll
        for (int ks = 0; ks < K1 / 32; ks++) {
            short8 av = *(const short8*)(a_base + ks * 32);
#pragma unroll
            for (int nt = 0; nt < NT; nt++) {
                short8 bv = *(const short8*)(b_base + nt * 16 * KP + ks * 32);
                acc1[ch][nt] = __builtin_amdgcn_mfma_f32_16x16x32_bf16(av, bv, acc1[ch][nt], 0, 0, 0);
            }
        }
    }

    // ---- epilogue 1: op -> Xs (bf16) ----
    if constexpr (MODE == 0) {
#pragma unroll
        for (int ch = 0; ch < NC1; ch++)
#pragma unroll
            for (int nt = 0; nt < NT; nt++)
#pragma unroll
                for (int r = 0; r < 4; r++) {
                    float v = fmaxf(acc1[ch][nt][r], 0.0f);
                    Xs[(16 * w + lq * 4 + r) * KP + ch * CH + nt * 16 + lm] = f2bf(v);
                }
    } else {
        // l2norm over the full row, relu, dropout (keep-prob 0.5, JAX threefry bits)
        float ss[4] = {0.f, 0.f, 0.f, 0.f};
#pragma unroll
        for (int ch = 0; ch < NC1; ch++)
#pragma unroll
            for (int nt = 0; nt < NT; nt++)
#pragma unroll
                for (int r = 0; r < 4; r++)
                    ss[r] = fmaf(acc1[ch][nt][r], acc1[ch][nt][r], ss[r]);
#pragma unroll
        for (int r = 0; r < 4; r++) {
#pragma unroll
            for (int m = 1; m <= 8; m <<= 1) ss[r] += __shfl_xor(ss[r], m, 64);
        }
        const int grow = row0 + 16 * w + lq * 4;
#pragma unroll
        for (int r = 0; r < 4; r++) {
            const float d = fmaxf(sqrtf(ss[r]), 1e-12f);
#pragma unroll
            for (int ch = 0; ch < NC1; ch++)
#pragma unroll
                for (int nt = 0; nt < NT; nt++) {
                    float y = fmaxf(acc1[ch][nt][r] / d, 0.0f);
                    int col = ch * CH + nt * 16 + lm;
                    uint32_t idx = (uint32_t)(grow + r) * (uint32_t)N1 + (uint32_t)col;
                    float u = jax_u01(jax_bits32(k0, k1, idx));
                    Xs[(16 * w + lq * 4 + r) * KP + col] = f2bf((u < 0.5f) ? y * 2.0f : 0.0f);
                }
        }
    }
    __syncthreads();   // Xs visible; Ws + As free

    // ---- GEMM2: Xs @ W2 -> C ----
    const uint16_t* a2_base = Xs + (16 * w + lm) * KP + lq * 8;
    uint16_t* sc = As + w * 16 * CHP;
    const int nch2 = Ntot2 / CH;
    for (int ch = 0; ch < nch2; ch++) {
        for (int i = tid; i < CH * KC; i += 256) {
            int r = i / KC, c = i - r * KC;
            *(uint4*)(Ws + r * KP + c * 8) =
                *(const uint4*)(g.W2 + (size_t)(ch * CH + r) * N1 + c * 8);
        }
        __syncthreads();

        floatx4 acc[NT];
#pragma unroll
        for (int nt = 0; nt < NT; nt++) acc[nt] = (floatx4){0.f, 0.f, 0.f, 0.f};
#pragma unroll
        for (int ks = 0; ks < N1 / 32; ks++) {
            short8 av = *(const short8*)(a2_base + ks * 32);
#pragma unroll
            for (int nt = 0; nt < NT; nt++) {
                short8 bv = *(const short8*)(b_base + nt * 16 * KP + ks * 32);
                acc[nt] = __builtin_amdgcn_mfma_f32_16x16x32_bf16(av, bv, acc[nt], 0, 0, 0);
            }
        }

#pragma unroll
        for (int nt = 0; nt < NT; nt++)
#pragma unroll
            for (int r = 0; r < 4; r++)
                sc[(lq * 4 + r) * CHP + nt * 16 + lm] = f2bf(acc[nt][r]);
        wave_lds_sync();

        constexpr int GPR = CH / 8;
#pragma unroll
        for (int it = 0; it < 2; it++) {
            int i = l + it * 64;
            int rr = i / GPR, cc = (i - rr * GPR) * 8;
            int gr = row0 + 16 * w + rr;
            if (gr < NN)
                *(uint4*)(g.C + (size_t)gr * Ntot2 + ch * CH + cc) = *(const uint4*)(sc + rr * CHP + cc);
        }
        __syncthreads();   // Ws + sc reads done before next chunk's staging
    }
}

// ======================= final: hmu=Amu@Wmu, hlv=Alv@Wlv, z=reparam(l2n(hmu),l2n(hlv)) ==========
__global__ __launch_bounds__(256) void final_gemm_k(const uint16_t* __restrict__ Amu,
                                                    const uint16_t* __restrict__ Alv,
                                                    const uint16_t* __restrict__ Wmu,
                                                    const uint16_t* __restrict__ Wlv,
                                                    float* __restrict__ out,
                                                    uint32_t k0, uint32_t k1)
{
    constexpr int K = 64, KP = K + 8, KC = K / 8, NT = 4;
    __shared__ uint16_t As[2][64 * KP];
    __shared__ uint16_t Ws[128 * KP];

    const int tid = threadIdx.x;
    const int row0 = blockIdx.x * 64;
    const int w  = tid >> 6;
    const int l  = tid & 63;
    const int lm = l & 15;
    const int lq = l >> 4;

    for (int i = tid; i < 64 * KC; i += 256) {
        int r = i / KC, c = i - r * KC;
        int gr = row0 + r; if (gr >= NN) gr = NN - 1;
        *(uint4*)(&As[0][r * KP + c * 8]) = *(const uint4*)(Amu + (size_t)gr * K + c * 8);
        *(uint4*)(&As[1][r * KP + c * 8]) = *(const uint4*)(Alv + (size_t)gr * K + c * 8);
    }
    for (int i = tid; i < 128 * KC; i += 256) {
        int r = i / KC, c = i - r * KC;
        uint4 v = (r < 64) ? *(const uint4*)(Wmu + (size_t)r * K + c * 8)
                           : *(const uint4*)(Wlv + (size_t)(r - 64) * K + c * 8);
        *(uint4*)(&Ws[r * KP + c * 8]) = v;
    }
    __syncthreads();

    const uint16_t* amu = &As[0][(16 * w + lm) * KP + lq * 8];
    const uint16_t* alv = &As[1][(16 * w + lm) * KP + lq * 8];
    const uint16_t* bmu = &Ws[lm * KP + lq * 8];
    const uint16_t* blv = &Ws[(64 + lm) * KP + lq * 8];

    floatx4 amu_acc[NT], alv_acc[NT];
#pragma unroll
    for (int nt = 0; nt < NT; nt++) {
        amu_acc[nt] = (floatx4){0.f, 0.f, 0.f, 0.f};
        alv_acc[nt] = (floatx4){0.f, 0.f, 0.f, 0.f};
    }
#pragma unroll
    for (int ks = 0; ks < K / 32; ks++) {
        short8 avm = *(const short8*)(amu + ks * 32);
        short8 avl = *(const short8*)(alv + ks * 32);
#pragma unroll
        for (int nt = 0; nt < NT; nt++) {
            short8 bvm = *(const short8*)(bmu + nt * 16 * KP + ks * 32);
            short8 bvl = *(const short8*)(blv + nt * 16 * KP + ks * 32);
            amu_acc[nt] = __builtin_amdgcn_mfma_f32_16x16x32_bf16(avm, bvm, amu_acc[nt], 0, 0, 0);
            alv_acc[nt] = __builtin_amdgcn_mfma_f32_16x16x32_bf16(avl, bvl, alv_acc[nt], 0, 0, 0);
        }
    }

    // row l2 norms (rows are wave-local: in-wave shuffle over the 16-lane column group)
    float smu[4] = {0.f, 0.f, 0.f, 0.f}, slv[4] = {0.f, 0.f, 0.f, 0.f};
#pragma unroll
    for (int nt = 0; nt < NT; nt++)
#pragma unroll
        for (int r = 0; r < 4; r++) {
            smu[r] = fmaf(amu_acc[nt][r], amu_acc[nt][r], smu[r]);
            slv[r] = fmaf(alv_acc[nt][r], alv_acc[nt][r], slv[r]);
        }
#pragma unroll
    for (int r = 0; r < 4; r++) {
#pragma unroll
        for (int m = 1; m <= 8; m <<= 1) {
            smu[r] += __shfl_xor(smu[r], m, 64);
            slv[r] += __shfl_xor(slv[r], m, 64);
        }
    }

    const float LO = -0.99999994f;
    const int grow = row0 + 16 * w + lq * 4;
#pragma unroll
    for (int r = 0; r < 4; r++) {
        const float dmu = fmaxf(sqrtf(smu[r]), 1e-12f);
        const float dlv = fmaxf(sqrtf(slv[r]), 1e-12f);
        const int gr = grow + r;
#pragma unroll
        for (int nt = 0; nt < NT; nt++) {
            float mu = amu_acc[nt][r] / dmu;
            float lv = alv_acc[nt][r] / dlv;
            uint32_t idx = (uint32_t)gr * 64u + (uint32_t)(nt * 16 + lm);
            float u01 = jax_u01(jax_bits32(k0, k1, idx));
            float u = fmaxf(LO, fmaf(u01, 2.0f, LO));
            float eps = 1.41421354f * erfinv_f(u);
            float stdv = expf(lv) + 1e-12f;
            if (gr < NN) out[idx] = fmaf(eps, stdv, mu);
        }
    }
}

// ======================= attention: 2 independent waves/block, 2-way batched =======================
struct AArg { const uint16_t* qkv; uint16_t* agg; };
struct AArgs2 { AArg a[2]; };

template<int DH>
__global__ __launch_bounds__(128) void attn_dual_k(AArgs2 as,
                                                   const int* __restrict__ rowptr,
                                                   const int* __restrict__ esrc,
                                                   float scale2, int str)
{
    constexpr int OD  = NH * DH;     // 128 / 64
    constexpr int QU  = DH / 8;      // uint4 loads per head slice (4 / 2)
    constexpr int CAP = 64;          // edges per chunk
    constexpr int NP  = CAP / 16;    // phase-1 passes (4)
    constexpr int FV  = OD / 16;     // dims per lane in phase 2 (8 / 4)
    constexpr int VW  = FV / 2;      // uint32 words per V slice (4 / 2)

    __shared__ float s_sc[2][CAP][4];
    __shared__ int   s_off[2][CAP];  // precomputed element offsets: src_node * str

    const uint16_t* qkv = as.a[blockIdx.y].qkv;
    uint16_t* agg       = as.a[blockIdx.y].agg;

    const int wv   = threadIdx.x >> 6;
    const int lane = threadIdx.x & 63;
    const int n    = blockIdx.x * 2 + wv;      // NN % 2 == 0
    const int h1   = lane & 3;
    const int e    = lane >> 2;
    const int g    = lane >> 4;
    const int dl   = lane & 15;
    const int h2   = dl >> 2;                  // head owning dims [dl*FV, dl*FV+FV)

    // q fragment kept PACKED (bf16x2 words) for v_dot2_f32_bf16
    uint32_t qw[DH / 2];
    {
        const uint4* q4 = (const uint4*)(qkv + (size_t)n * str + h1 * DH);
#pragma unroll
        for (int i = 0; i < QU; i++) {
            uint4 u = q4[i];
            qw[i * 4 + 0] = u.x; qw[i * 4 + 1] = u.y;
            qw[i * 4 + 2] = u.z; qw[i * 4 + 3] = u.w;
        }
    }

    const int j0 = rowptr[n], j1 = rowptr[n + 1];

    float m = -INFINITY, l = 0.0f;
    float acc[FV];
#pragma unroll
    for (int i = 0; i < FV; i++) acc[i] = 0.0f;

    const int voff = 2 * OD + dl * FV;

    for (int c0 = j0; c0 < j1; c0 += CAP) {
        const int cn = min(j1 - c0, CAP);

        if (lane < cn) s_off[wv][lane] = esrc[c0 + lane] * str;
        wave_lds_sync();

        // ---- V prefetch: first 16 edges, in flight concurrently with K gathers ----
        uint32_t vpre[4][VW];
#pragma unroll
        for (int t = 0; t < 4; t++) {
            const int j  = 4 * t + g;
            const int js = min(j, cn - 1);
            const uint16_t* vp = qkv + s_off[wv][js] + voff;
            if constexpr (VW == 4) {
                uint4 u = *(const uint4*)vp;
                vpre[t][0] = u.x; vpre[t][1] = u.y; vpre[t][2] = u.z; vpre[t][3] = u.w;
            } else {
                uint2 u = *(const uint2*)vp;
                vpre[t][0] = u.x; vpre[t][1] = u.y;
            }
        }

        // ---- phase 1: scores via packed bf16 dot2; passes processed in PAIRS with
        //      wave-uniform validity (npv), so both passes' K loads are in flight before
        //      either dot chain. No extra VALU for the dominant degree<=16 nodes.
        float p[NP];
        float lm = -INFINITY;
        const int npv = (cn + 15) >> 4;    // valid passes, wave-uniform
#pragma unroll
        for (int tt = 0; tt < NP; tt += 2) {
            float sA = -INFINITY, sB = -INFINITY;
            if (tt < npv) {                          // uniform branch
                const int jA = e + 16 * tt;
                const int jB = jA + 16;
                const bool hasB = (tt + 1 < npv);    // uniform
                uint4 ka[QU], kb[QU];
                {
                    const uint4* kp = (const uint4*)(qkv + s_off[wv][min(jA, cn - 1)] + OD + h1 * DH);
#pragma unroll
                    for (int i = 0; i < QU; i++) ka[i] = kp[i];
                }
                if (hasB) {
                    const uint4* kp = (const uint4*)(qkv + s_off[wv][min(jB, cn - 1)] + OD + h1 * DH);
#pragma unroll
                    for (int i = 0; i < QU; i++) kb[i] = kp[i];
                }
                float a0 = 0.0f, a1 = 0.0f;
#pragma unroll
                for (int i = 0; i < QU; i++) {
                    dot2bf(a0, qw[i * 4 + 0], ka[i].x);
                    dot2bf(a1, qw[i * 4 + 1], ka[i].y);
                    dot2bf(a0, qw[i * 4 + 2], ka[i].z);
                    dot2bf(a1, qw[i * 4 + 3], ka[i].w);
                }
                if (jA < cn) sA = (a0 + a1) * scale2;
                if (hasB) {
                    float b0 = 0.0f, b1 = 0.0f;
#pragma unroll
                    for (int i = 0; i < QU; i++) {
                        dot2bf(b0, qw[i * 4 + 0], kb[i].x);
                        dot2bf(b1, qw[i * 4 + 1], kb[i].y);
                        dot2bf(b0, qw[i * 4 + 2], kb[i].z);
                        dot2bf(b1, qw[i * 4 + 3], kb[i].w);
                    }
                    if (jB < cn) sB = (b0 + b1) * scale2;
                }
            }
            p[tt] = sA; p[tt + 1] = sB;
            lm = fmaxf(lm, fmaxf(sA, sB));
        }
#pragma unroll
        for (int msk = 4; msk <= 32; msk <<= 1) lm = fmaxf(lm, __shfl_xor(lm, msk, 64));
        const float mn = fmaxf(m, lm);
        const float corr = exp2f(m - mn);   // first chunk: exp2(-inf)=0 (acc already 0)
        m = mn;

        float ls = 0.0f;
#pragma unroll
        for (int t = 0; t < NP; t++) {
            const int j = e + 16 * t;
            float pe = 0.0f;
            if (j < cn) {
                pe = exp2f(p[t] - mn);
                s_sc[wv][j][h1] = pe;
            }
            ls += pe;
        }
#pragma unroll
        for (int msk = 4; msk <= 32; msk <<= 1) ls += __shfl_xor(ls, msk, 64);
        l = l * corr + ls;
        wave_lds_sync();

        // ---- phase 2: accumulate prefetched V (first 16 edges), then rare tail ----
        const float c2 = __shfl(corr, h2, 64);   // lane h2 has h1 == h2
#pragma unroll
        for (int i = 0; i < FV; i++) acc[i] *= c2;

#pragma unroll
        for (int t = 0; t < 4; t++) {
            const int j  = 4 * t + g;
            const int js = min(j, cn - 1);
            const float av = s_sc[wv][js][h2];
            const float alpha = (j < cn) ? av : 0.0f;
#pragma unroll
            for (int i = 0; i < VW; i++) {
                float lo, hi;
                unpk2(vpre[t][i], lo, hi);
                acc[2 * i + 0] = fmaf(alpha, lo, acc[2 * i + 0]);
                acc[2 * i + 1] = fmaf(alpha, hi, acc[2 * i + 1]);
            }
        }

        for (int jb = 16; jb < cn; jb += 4) {
            const int j = jb + g;
            if (j < cn) {
                const float alpha = s_sc[wv][j][h2];
                const uint16_t* vp = qkv + s_off[wv][j] + voff;
                if constexpr (FV == 8) {
                    uint4 u = *(const uint4*)vp;
                    float vf[8];
                    unpk8(u, vf);
#pragma unroll
                    for (int i = 0; i < 8; i++) acc[i] = fmaf(alpha, vf[i], acc[i]);
                } else {
                    uint2 u = *(const uint2*)vp;
                    float f0, f1, f2v, f3v;
                    unpk2(u.x, f0, f1);
                    unpk2(u.y, f2v, f3v);
                    acc[0] = fmaf(alpha, f0,  acc[0]);
                    acc[1] = fmaf(alpha, f1,  acc[1]);
                    acc[2] = fmaf(alpha, f2v, acc[2]);
                    acc[3] = fmaf(alpha, f3v, acc[3]);
                }
            }
        }
        wave_lds_sync();   // phase-2 LDS reads done before next chunk's s_off writes
    }

    // ---- epilogue: reduce over g, normalize, write ----
    const float lh = __shfl(l, h2, 64);
    const float inv = (lh > 0.0f) ? 1.0f / lh : 0.0f;
#pragma unroll
    for (int i = 0; i < FV; i++) {
        acc[i] += __shfl_xor(acc[i], 16, 64);
        acc[i] += __shfl_xor(acc[i], 32, 64);
    }
    if (g == 0) {
        uint16_t* op = agg + (size_t)n * OD + dl * FV;
        uint32_t wword[FV / 2];
#pragma unroll
        for (int i = 0; i < FV / 2; i++)
            wword[i] = (uint32_t)f2bf(acc[2 * i] * inv) | ((uint32_t)f2bf(acc[2 * i + 1] * inv) << 16);
        if constexpr (FV == 8) {
            *(uint4*)op = make_uint4(wword[0], wword[1], wword[2], wword[3]);
        } else {
            *(uint2*)op = make_uint2(wword[0], wword[1]);
        }
    }
}

// ======================= host side =======================
extern "C" void kernel_launch(void* const* d_in, const int* in_sizes, int n_in,
                              void* d_out, int out_size, void* d_ws, size_t ws_size,
                              hipStream_t stream)
{
    const float* feat    = (const float*)d_in[0];
    const int*   src     = (const int*)d_in[1];
    const int*   dst     = (const int*)d_in[2];
    const float* wqkv1_0 = (const float*)d_in[3];
    const float* wqkv1_r = (const float*)d_in[4];
    const float* wo1     = (const float*)d_in[5];
    const float* wqkv2_0 = (const float*)d_in[6];
    const float* wqkv2_r = (const float*)d_in[7];
    const float* wo2     = (const float*)d_in[8];
    const float* wqkv3_0 = (const float*)d_in[9];
    const float* wqkv3_r = (const float*)d_in[10];
    const float* wo3     = (const float*)d_in[11];
    float* out = (float*)d_out;

    char* wp = (char*)d_ws;
    auto alloc = [&](size_t bytes) { char* p = wp; wp += (bytes + 255) & ~(size_t)255; return p; };

    // ---- weight segments; gc2/gc3 qkv pairs adjacent for combined GEMMs ----
    WSegs segs;
    int offs[18];
    int acc_off = 0;
    auto seg = [&](int i, const float* p, int Bc, int Kc, int Cc) {
        segs.s[i].src = p; segs.s[i].B = Bc; segs.s[i].K = Kc; segs.s[i].C = Cc;
        segs.s[i].off = acc_off; offs[i] = acc_off; acc_off += Bc * Kc * Cc;
    };
    seg(0,  wqkv1_0,                 3, 256, 128);
    seg(1,  wqkv1_r,                 3, 128, 128);
    seg(2,  wqkv1_r + 3 * 128 * 128, 3, 128, 128);
    seg(3,  wo1,                     1, 128, 128);
    seg(4,  wo1 + 128 * 128,         1, 128, 128);
    seg(5,  wo1 + 2 * 128 * 128,     1, 128, 128);
    seg(6,  wqkv2_0,                 3, 128, 64);   // } contiguous 384 rows, K=128
    seg(7,  wqkv3_0,                 3, 128, 64);   // }
    seg(8,  wqkv2_r,                 3, 64, 64);
    seg(9,  wqkv3_r,                 3, 64, 64);
    seg(10, wqkv2_r + 3 * 64 * 64,   3, 64, 64);
    seg(11, wqkv3_r + 3 * 64 * 64,   3, 64, 64);
    seg(12, wo2,                     1, 64, 64);
    seg(13, wo2 + 64 * 64,           1, 64, 64);
    seg(14, wo2 + 2 * 64 * 64,       1, 64, 64);
    seg(15, wo3,                     1, 64, 64);
    seg(16, wo3 + 64 * 64,           1, 64, 64);
    seg(17, wo3 + 2 * 64 * 64,       1, 64, 64);

    uint16_t* Wt     = (uint16_t*)alloc((size_t)acc_off * 2);
    uint16_t* qkvL   = (uint16_t*)alloc((size_t)NN * 384 * 2);  // gc1 qkv / gc2+gc3 L1 combined
    uint16_t* agg128 = (uint16_t*)alloc((size_t)NN * 128 * 2);
    uint16_t* qkv_mu = (uint16_t*)alloc((size_t)NN * 192 * 2);
    uint16_t* qkv_lv = (uint16_t*)alloc((size_t)NN * 192 * 2);
    uint16_t* agg_mu = (uint16_t*)alloc((size_t)NN * 64 * 2);
    uint16_t* agg_lv = (uint16_t*)alloc((size_t)NN * 64 * 2);
    int* rowptr = (int*)alloc((size_t)(NN + 1) * 4);
    int* cursor = (int*)alloc((size_t)NN * 4);
    int* bsums  = (int*)alloc((size_t)SCAN_NBLK * 4);
    int* esrc   = (int*)alloc((size_t)NE * 4);

    wconv_k<<<dim3(384, 18), 256, 0, stream>>>(segs, Wt);

    fill_u32_k<<<(NN + 255) / 256, 256, 0, stream>>>((uint32_t*)cursor, 0u, NN);
    hist_k<<<(NE + 255) / 256, 256, 0, stream>>>(dst, cursor);
    scan1_k<<<SCAN_NBLK, 256, 0, stream>>>(cursor, rowptr, bsums);
    scan2_k<<<1, 64, 0, stream>>>(bsums);
    scan3_k<<<(NN + 255) / 256, 256, 0, stream>>>(rowptr, bsums, cursor);
    csr_scatter_k<<<(NE + 255) / 256, 256, 0, stream>>>(src, dst, cursor, esrc);

    uint32_t kd0, kd1, ke0, ke1;
    tf2x32(0u, 42u, 0u, 0u, kd0, kd1);
    tf2x32(0u, 42u, 0u, 1u, ke0, ke1);

    const int GX = (NN + 63) / 64;   // 782
    const float LOG2E = 1.4426950408889634f;
    const float sc32 = LOG2E / sqrtf(32.0f);
    const float sc16 = 0.25f * LOG2E;

    auto a1 = [&](AArg a) { AArgs2 r; r.a[0] = a; r.a[1] = a; return r; };
    auto a2 = [&](AArg a0, AArg b0) { AArgs2 r; r.a[0] = a0; r.a[1] = b0; return r; };
    auto f1 = [&](F2Arg a) { F2Args2 r; r.a[0] = a; r.a[1] = a; return r; };
    auto f2 = [&](F2Arg a0, F2Arg b0) { F2Args2 r; r.a[0] = a0; r.a[1] = b0; return r; };

    // LDS sizes
    const size_t L256_64 = (size_t)(64 + 64) * (256 + 8) * 2;   // 67584 (feat GEMM, CH=64)
    const size_t LF128   = (size_t)192 * (128 + 8) * 2;         // 52224 (fused K=128)
    const size_t LF64    = (size_t)192 * (64 + 8) * 2;          // 27648 (fused K=64)

    // ================= gc1 (od=128) =================
    // feat qkv GEMM: 3-way N-split (y = 128-col slice of the 384 outputs)
    GArg3 gf;
    for (int y = 0; y < 3; y++)
        gf.a[y] = GArg{feat, Wt + offs[0] + (size_t)y * 128 * 256, qkvL + y * 128};
    gemm_mfma_k<256, 64, true><<<dim3(GX, 3), 256, L256_64, stream>>>(gf, 384, 128, 0);
    attn_dual_k<32><<<dim3(NN / 2, 1), 128, 0, stream>>>(a1({qkvL, agg128}), rowptr, esrc, sc32, 384);

    // h = relu(agg@wo1_0); qkv = h@wqkv1_r0
    fused2_k<128, 0><<<dim3(GX, 1), 256, LF128, stream>>>(
        f1({agg128, Wt + offs[3], Wt + offs[1], qkvL}), 384, 0u, 0u);
    attn_dual_k<32><<<dim3(NN / 2, 1), 128, 0, stream>>>(a1({qkvL, agg128}), rowptr, esrc, sc32, 384);

    // h = relu(agg@wo1_1); qkv = h@wqkv1_r1
    fused2_k<128, 0><<<dim3(GX, 1), 256, LF128, stream>>>(
        f1({agg128, Wt + offs[4], Wt + offs[2], qkvL}), 384, 0u, 0u);
    attn_dual_k<32><<<dim3(NN / 2, 1), 128, 0, stream>>>(a1({qkvL, agg128}), rowptr, esrc, sc32, 384);

    // h = agg@wo1_2 (no relu); x = drop(relu(l2norm(h))); qkvL = x@[wqkv2_0|wqkv3_0]
    fused2_k<128, 1><<<dim3(GX, 1), 256, LF128, stream>>>(
        f1({agg128, Wt + offs[5], Wt + offs[6], qkvL}), 384, kd0, kd1);

    // ================= gc2 + gc3 batched (od=64) =================
    attn_dual_k<16><<<dim3(NN / 2, 2), 128, 0, stream>>>(
        a2({qkvL, agg_mu}, {qkvL + 192, agg_lv}), rowptr, esrc, sc16, 384);

    // h = relu(agg@wo_0); qkv = h@wqkv_r0  (mu | lv)
    fused2_k<64, 0><<<dim3(GX, 2), 256, LF64, stream>>>(
        f2({agg_mu, Wt + offs[12], Wt + offs[8],  qkv_mu},
           {agg_lv, Wt + offs[15], Wt + offs[9],  qkv_lv}), 192, 0u, 0u);
    attn_dual_k<16><<<dim3(NN / 2, 2), 128, 0, stream>>>(
        a2({qkv_mu, agg_mu}, {qkv_lv, agg_lv}), rowptr, esrc, sc16, 192);

    fused2_k<64, 0><<<dim3(GX, 2), 256, LF64, stream>>>(
        f2({agg_mu, Wt + offs[13], Wt + offs[10], qkv_mu},
           {agg_lv, Wt + offs[16], Wt + offs[11], qkv_lv}), 192, 0u, 0u);
    attn_dual_k<16><<<dim3(NN / 2, 2), 128, 0, stream>>>(
        a2({qkv_mu, agg_mu}, {qkv_lv, agg_lv}), rowptr, esrc, sc16, 192);

    // hmu = agg_mu@wo2_2, hlv = agg_lv@wo3_2, z = reparam(l2n(hmu), l2n(hlv))
    final_gemm_k<<<dim3(GX, 1), 256, 0, stream>>>(
        agg_mu, agg_lv, Wt + offs[14], Wt + offs[17], out, ke0, ke1);
}

// Round 8
// 756.549 us; speedup vs baseline: 1.0690x; 1.0690x over previous
//
#include <hip/hip_runtime.h>
#include <stdint.h>
#include <math.h>

#define NN 50000          // nodes
#define NE 800000         // edges
#define NH 4              // heads

typedef __attribute__((ext_vector_type(8))) short short8;
typedef __attribute__((ext_vector_type(4))) float floatx4;

// ======================= bf16 helpers =======================
__device__ inline float bf2f(uint32_t u16)
{
    return __uint_as_float(u16 << 16);
}
__device__ inline uint16_t f2bf(float f)
{
    uint32_t u = __float_as_uint(f);
    uint32_t r = (u + 0x7fffu + ((u >> 16) & 1u)) >> 16;   // RNE
    return (uint16_t)r;
}
// 2-op unpack of a packed bf16x2 word
__device__ inline void unpk2(uint32_t w, float& lo, float& hi)
{
    lo = __uint_as_float(w << 16);
    hi = __uint_as_float(w & 0xffff0000u);
}
__device__ inline void unpk8(uint4 u, float* f)
{
    unpk2(u.x, f[0], f[1]);
    unpk2(u.y, f[2], f[3]);
    unpk2(u.z, f[4], f[5]);
    unpk2(u.w, f[6], f[7]);
}

// packed bf16x2 dot with f32 accumulate: s += a.lo*b.lo + a.hi*b.hi
__device__ inline void dot2bf(float& s, uint32_t a, uint32_t b)
{
    asm("v_dot2_f32_bf16 %0, %1, %2, %0" : "+v"(s) : "v"(a), "v"(b));
}

// intra-wave LDS producer->consumer sync (single wave; no __syncthreads needed)
__device__ inline void wave_lds_sync()
{
    __builtin_amdgcn_wave_barrier();
    asm volatile("s_waitcnt lgkmcnt(0)" ::: "memory");
    __builtin_amdgcn_wave_barrier();
}

// ======================= JAX threefry2x32 (partitionable mode) =======================
__host__ __device__ inline void tf2x32(uint32_t k0, uint32_t k1,
                                       uint32_t x0, uint32_t x1,
                                       uint32_t& o0, uint32_t& o1)
{
    uint32_t ks2 = k0 ^ k1 ^ 0x1BD11BDAu;
    x0 += k0; x1 += k1;
#define TF_R(r) { x0 += x1; x1 = (x1 << (r)) | (x1 >> (32 - (r))); x1 ^= x0; }
    TF_R(13) TF_R(15) TF_R(26) TF_R(6)
    x0 += k1;  x1 += ks2 + 1u;
    TF_R(17) TF_R(29) TF_R(16) TF_R(24)
    x0 += ks2; x1 += k0 + 2u;
    TF_R(13) TF_R(15) TF_R(26) TF_R(6)
    x0 += k0;  x1 += k1 + 3u;
    TF_R(17) TF_R(29) TF_R(16) TF_R(24)
    x0 += k1;  x1 += ks2 + 4u;
    TF_R(13) TF_R(15) TF_R(26) TF_R(6)
    x0 += ks2; x1 += k0 + 5u;
#undef TF_R
    o0 = x0; o1 = x1;
}

__device__ inline uint32_t jax_bits32(uint32_t k0, uint32_t k1, uint32_t idx)
{
    uint32_t a, b;
    tf2x32(k0, k1, 0u, idx, a, b);
    return a ^ b;
}

__device__ inline float jax_u01(uint32_t bits)
{
    return __uint_as_float((bits >> 9) | 0x3f800000u) - 1.0f;
}

// XLA ErfInv32 (Giles 2012)
__device__ inline float erfinv_f(float x)
{
    float w = -log1pf(-x * x);
    float p;
    if (w < 5.0f) {
        w = w - 2.5f;
        p = 2.81022636e-08f;
        p = fmaf(p, w, 3.43273939e-07f);
        p = fmaf(p, w, -3.5233877e-06f);
        p = fmaf(p, w, -4.39150654e-06f);
        p = fmaf(p, w, 0.00021858087f);
        p = fmaf(p, w, -0.00125372503f);
        p = fmaf(p, w, -0.00417768164f);
        p = fmaf(p, w, 0.246640727f);
        p = fmaf(p, w, 1.50140941f);
    } else {
        w = sqrtf(w) - 3.0f;
        p = -0.000200214257f;
        p = fmaf(p, w, 0.000100950558f);
        p = fmaf(p, w, 0.00134934322f);
        p = fmaf(p, w, -0.00367342844f);
        p = fmaf(p, w, 0.00573950773f);
        p = fmaf(p, w, -0.0076224613f);
        p = fmaf(p, w, 0.00943887047f);
        p = fmaf(p, w, 1.00167406f);
        p = fmaf(p, w, 2.83297682f);
    }
    return p * x;
}

// ======================= utility kernels =======================
__global__ __launch_bounds__(256) void fill_u32_k(uint32_t* p, uint32_t v, int n)
{
    int i = blockIdx.x * blockDim.x + threadIdx.x;
    if (i < n) p[i] = v;
}

// ======================= weight convert: fp32 [B][K][C] -> bf16 Wt [B*C][K] =======================
struct WSeg { const float* src; int B, K, C, off; };
struct WSegs { WSeg s[18]; };

__global__ __launch_bounds__(256) void wconv_k(WSegs segs, uint16_t* __restrict__ Wt)
{
    WSeg sg = segs.s[blockIdx.y];
    int n = sg.B * sg.K * sg.C;
    int i = blockIdx.x * 256 + threadIdx.x;
    if (i >= n) return;
    int kc = sg.K * sg.C;
    int b = i / kc;
    int rr = i - b * kc;
    int k = rr / sg.C;
    int c = rr - k * sg.C;
    Wt[(size_t)sg.off + (size_t)(b * sg.C + c) * sg.K + k] = f2bf(sg.src[i]);
}

// ======================= CSR build (once per launch) =======================
__global__ __launch_bounds__(256) void hist_k(const int* __restrict__ dst, int* __restrict__ deg)
{
    int e = blockIdx.x * blockDim.x + threadIdx.x;
    if (e < NE) atomicAdd(&deg[dst[e]], 1);
}

#define SCAN_CHUNK 1024
#define SCAN_NBLK  ((NN + SCAN_CHUNK - 1) / SCAN_CHUNK)   // 49

__global__ __launch_bounds__(256) void scan1_k(const int* __restrict__ deg,
                                               int* __restrict__ rowptr,
                                               int* __restrict__ bsums)
{
    __shared__ int lds[256];
    int b = blockIdx.x, t = threadIdx.x;
    int base = b * SCAN_CHUNK + t * 4;
    int v0 = (base + 0 < NN) ? deg[base + 0] : 0;
    int v1 = (base + 1 < NN) ? deg[base + 1] : 0;
    int v2 = (base + 2 < NN) ? deg[base + 2] : 0;
    int v3 = (base + 3 < NN) ? deg[base + 3] : 0;
    int s = v0 + v1 + v2 + v3;
    lds[t] = s;
    __syncthreads();
    for (int off = 1; off < 256; off <<= 1) {
        int x = (t >= off) ? lds[t - off] : 0;
        __syncthreads();
        lds[t] += x;
        __syncthreads();
    }
    int excl = lds[t] - s;
    if (base + 0 < NN) rowptr[base + 0] = excl;
    if (base + 1 < NN) rowptr[base + 1] = excl + v0;
    if (base + 2 < NN) rowptr[base + 2] = excl + v0 + v1;
    if (base + 3 < NN) rowptr[base + 3] = excl + v0 + v1 + v2;
    if (t == 255) bsums[b] = lds[255];
}

__global__ void scan2_k(int* bsums)
{
    if (threadIdx.x == 0 && blockIdx.x == 0) {
        int run = 0;
        for (int i = 0; i < SCAN_NBLK; i++) { int t = bsums[i]; bsums[i] = run; run += t; }
    }
}

__global__ __launch_bounds__(256) void scan3_k(int* __restrict__ rowptr,
                                               const int* __restrict__ bsums,
                                               int* __restrict__ cursor)
{
    int i = blockIdx.x * blockDim.x + threadIdx.x;
    if (i < NN) {
        int r = rowptr[i] + bsums[i / SCAN_CHUNK];
        rowptr[i] = r;
        cursor[i] = r;
    }
    if (i == 0) rowptr[NN] = NE;
}

__global__ __launch_bounds__(256) void csr_scatter_k(const int* __restrict__ src,
                                                     const int* __restrict__ dst,
                                                     int* __restrict__ cursor,
                                                     int* __restrict__ esrc)
{
    int e = blockIdx.x * blockDim.x + threadIdx.x;
    if (e >= NE) return;
    int d = dst[e];
    int pos = atomicAdd(&cursor[d], 1);
    esrc[pos] = src[e];
}

// ======================= bf16 MFMA GEMM (feat qkv GEMM; 3-way N-split via blockIdx.y) =========
struct GArg { const void* A; const uint16_t* W; uint16_t* C; };
struct GArg3 { GArg a[3]; };

template<int K, int CH, bool AF32>
__global__ __launch_bounds__(256) void gemm_mfma_k(GArg3 gs, int Ntot, int ncols, int relu)
{
    constexpr int KP = K + 8;
    constexpr int KC = K / 8;
    constexpr int NT = CH / 16;
    constexpr int CHP = CH + 8;          // epilogue scratch row pitch
    constexpr int NIT = (2 * CH) / 64;   // store iterations per lane
    static_assert(64 * CHP <= CH * KP, "epilogue scratch must fit in Ws");
    extern __shared__ uint16_t smem[];
    uint16_t* As = smem;             // 64 x KP
    uint16_t* Ws = smem + 64 * KP;   // CH x KP (doubles as epilogue scratch)

    const GArg g = gs.a[blockIdx.y];
    const uint16_t* W = g.W;
    uint16_t* C = g.C;

    const int tid = threadIdx.x;
    const int row0 = blockIdx.x * 64;
    const int w  = tid >> 6;
    const int l  = tid & 63;
    const int lm = l & 15;
    const int lq = l >> 4;

    for (int i = tid; i < 64 * KC; i += 256) {
        int r = i / KC, c = i - r * KC;
        int gr = row0 + r; if (gr >= NN) gr = NN - 1;
        if constexpr (AF32) {
            const float* Af = (const float*)g.A + (size_t)gr * K + c * 8;
            float4 f0 = *(const float4*)Af;
            float4 f1 = *(const float4*)(Af + 4);
            uint4 vv;
            vv.x = (uint32_t)f2bf(f0.x) | ((uint32_t)f2bf(f0.y) << 16);
            vv.y = (uint32_t)f2bf(f0.z) | ((uint32_t)f2bf(f0.w) << 16);
            vv.z = (uint32_t)f2bf(f1.x) | ((uint32_t)f2bf(f1.y) << 16);
            vv.w = (uint32_t)f2bf(f1.z) | ((uint32_t)f2bf(f1.w) << 16);
            *(uint4*)(As + r * KP + c * 8) = vv;
        } else {
            uint4 vv = *(const uint4*)((const uint16_t*)g.A + (size_t)gr * K + c * 8);
            *(uint4*)(As + r * KP + c * 8) = vv;
        }
    }

    const uint16_t* a_base = As + (16 * w + lm) * KP + lq * 8;
    const uint16_t* b_base = Ws + lm * KP + lq * 8;
    uint16_t* sc = Ws + w * 16 * CHP;

    const int nchunks = ncols / CH;
    for (int ch = 0; ch < nchunks; ch++) {
        __syncthreads();
        for (int i = tid; i < CH * KC; i += 256) {
            int r = i / KC, c = i - r * KC;
            uint4 vv = *(const uint4*)(W + (size_t)(ch * CH + r) * K + c * 8);
            *(uint4*)(Ws + r * KP + c * 8) = vv;
        }
        __syncthreads();

        floatx4 acc[NT];
#pragma unroll
        for (int nt = 0; nt < NT; nt++) acc[nt] = (floatx4){0.f, 0.f, 0.f, 0.f};

#pragma unroll
        for (int ks = 0; ks < K / 32; ks++) {
            short8 av = *(const short8*)(a_base + ks * 32);
#pragma unroll
            for (int nt = 0; nt < NT; nt++) {
                short8 bv = *(const short8*)(b_base + nt * 16 * KP + ks * 32);
                acc[nt] = __builtin_amdgcn_mfma_f32_16x16x32_bf16(av, bv, acc[nt], 0, 0, 0);
            }
        }

        __syncthreads();   // Ws reads done -> reuse as scratch

#pragma unroll
        for (int nt = 0; nt < NT; nt++) {
#pragma unroll
            for (int r = 0; r < 4; r++) {
                float v = acc[nt][r];
                if (relu) v = fmaxf(v, 0.0f);
                sc[(lq * 4 + r) * CHP + nt * 16 + lm] = f2bf(v);
            }
        }
        wave_lds_sync();

        constexpr int GPR = CH / 8;
#pragma unroll
        for (int it = 0; it < NIT; it++) {
            int i = l + it * 64;
            int rr = i / GPR, cc = (i - rr * GPR) * 8;
            int gr = row0 + 16 * w + rr;
            if (gr < NN) {
                uint4 vv = *(const uint4*)(sc + rr * CHP + cc);
                *(uint4*)(C + (size_t)gr * Ntot + ch * CH + cc) = vv;
            }
        }
    }
}

// ======================= fused GEMM pair: C2 = op(A @ W1) @ W2 =======================
// LDS reduced to TWO regions: AXs holds the A-tile during GEMM1 and is overwritten in place
// (per-wave row stripes -> wave-local hazard only) by the op() intermediate for GEMM2.
// The C-store scratch overlays Ws after a barrier (R4-proven pattern). K=128: 34.8KB
// (4 blocks/CU vs 3); K=64: 18.4KB (8 blocks/CU vs 5) -> staging latency hidden by TLP.
struct F2Arg { const uint16_t* A; const uint16_t* W1; const uint16_t* W2; uint16_t* C; };
struct F2Args2 { F2Arg a[2]; };

template<int K1, int MODE>
__global__ __launch_bounds__(256) void fused2_k(F2Args2 fs, int Ntot2, uint32_t k0, uint32_t k1)
{
    constexpr int N1 = K1;
    constexpr int CH = 64;
    constexpr int KP = K1 + 8;
    constexpr int KC = K1 / 8;
    constexpr int NC1 = N1 / CH;     // 2 (K1=128) or 1 (K1=64)
    constexpr int NT = CH / 16;      // 4
    constexpr int CHP = CH + 8;
    static_assert(64 * CHP <= CH * KP, "store scratch must fit in Ws");
    extern __shared__ uint16_t smem[];
    uint16_t* AXs = smem;            // 64 x KP: A tile (GEMM1), then X tile (GEMM2)
    uint16_t* Ws  = AXs + 64 * KP;   // CH x KP: weight staging (both GEMMs) + store scratch

    const F2Arg g = fs.a[blockIdx.y];
    const int tid = threadIdx.x;
    const int row0 = blockIdx.x * 64;
    const int w  = tid >> 6;
    const int l  = tid & 63;
    const int lm = l & 15;
    const int lq = l >> 4;

    // ---- stage A (64 x K1) ----
    for (int i = tid; i < 64 * KC; i += 256) {
        int r = i / KC, c = i - r * KC;
        int gr = row0 + r; if (gr >= NN) gr = NN - 1;
        *(uint4*)(AXs + r * KP + c * 8) = *(const uint4*)(g.A + (size_t)gr * K1 + c * 8);
    }

    const uint16_t* a_base = AXs + (16 * w + lm) * KP + lq * 8;
    const uint16_t* b_base = Ws + lm * KP + lq * 8;

    // ---- GEMM1: acc over all N1 columns, held in registers across chunks ----
    floatx4 acc1[NC1][NT];
#pragma unroll
    for (int ch = 0; ch < NC1; ch++)
#pragma unroll
        for (int nt = 0; nt < NT; nt++) acc1[ch][nt] = (floatx4){0.f, 0.f, 0.f, 0.f};

#pragma unroll
    for (int ch = 0; ch < NC1; ch++) {
        __syncthreads();   // A staged (ch 0) / previous chunk's Ws reads done
        for (int i = tid; i < CH * KC; i += 256) {
            int r = i / KC, c = i - r * KC;
            *(uint4*)(Ws + r * KP + c * 8) =
                *(const uint4*)(g.W1 + (size_t)(ch * CH + r) * K1 + c * 8);
        }
        __syncthreads();
#pragma unroll
        for (int ks = 0; ks < K1 / 32; ks++) {
            short8 av = *(const short8*)(a_base + ks * 32);
#pragma unroll
            for (int nt = 0; nt < NT; nt++) {
                short8 bv = *(const short8*)(b_base + nt * 16 * KP + ks * 32);
                acc1[ch][nt] = __builtin_amdgcn_mfma_f32_16x16x32_bf16(av, bv, acc1[ch][nt], 0, 0, 0);
            }
        }
    }

    // ---- epilogue 1: op -> X, written in place over the A tile. Wave w only ever
    //      reads/writes rows [16w, 16w+16) of AXs in GEMM1 MFMA / here / GEMM2 MFMA,
    //      so the overwrite is a wave-local hazard: wave_lds_sync suffices.
    wave_lds_sync();   // own MFMA ds_reads of A retired
    if constexpr (MODE == 0) {
#pragma unroll
        for (int ch = 0; ch < NC1; ch++)
#pragma unroll
            for (int nt = 0; nt < NT; nt++)
#pragma unroll
                for (int r = 0; r < 4; r++) {
                    float v = fmaxf(acc1[ch][nt][r], 0.0f);
                    AXs[(16 * w + lq * 4 + r) * KP + ch * CH + nt * 16 + lm] = f2bf(v);
                }
    } else {
        // l2norm over the full row, relu, dropout (keep-prob 0.5, JAX threefry bits)
        float ss[4] = {0.f, 0.f, 0.f, 0.f};
#pragma unroll
        for (int ch = 0; ch < NC1; ch++)
#pragma unroll
            for (int nt = 0; nt < NT; nt++)
#pragma unroll
                for (int r = 0; r < 4; r++)
                    ss[r] = fmaf(acc1[ch][nt][r], acc1[ch][nt][r], ss[r]);
#pragma unroll
        for (int r = 0; r < 4; r++) {
#pragma unroll
            for (int m = 1; m <= 8; m <<= 1) ss[r] += __shfl_xor(ss[r], m, 64);
        }
        const int grow = row0 + 16 * w + lq * 4;
#pragma unroll
        for (int r = 0; r < 4; r++) {
            const float d = fmaxf(sqrtf(ss[r]), 1e-12f);
#pragma unroll
            for (int ch = 0; ch < NC1; ch++)
#pragma unroll
                for (int nt = 0; nt < NT; nt++) {
                    float y = fmaxf(acc1[ch][nt][r] / d, 0.0f);
                    int col = ch * CH + nt * 16 + lm;
                    uint32_t idx = (uint32_t)(grow + r) * (uint32_t)N1 + (uint32_t)col;
                    float u = jax_u01(jax_bits32(k0, k1, idx));
                    AXs[(16 * w + lq * 4 + r) * KP + col] = f2bf((u < 0.5f) ? y * 2.0f : 0.0f);
                }
        }
    }

    // ---- GEMM2: X @ W2 -> C (a_base now reads the X tile at the same addresses) ----
    uint16_t* sc = Ws + w * 16 * CHP;    // store scratch overlays Ws after barrier
    const int nch2 = Ntot2 / CH;
    for (int ch = 0; ch < nch2; ch++) {
        __syncthreads();   // all waves done with GEMM1/prev-chunk Ws reads + sc reads
        for (int i = tid; i < CH * KC; i += 256) {
            int r = i / KC, c = i - r * KC;
            *(uint4*)(Ws + r * KP + c * 8) =
                *(const uint4*)(g.W2 + (size_t)(ch * CH + r) * N1 + c * 8);
        }
        __syncthreads();

        floatx4 acc[NT];
#pragma unroll
        for (int nt = 0; nt < NT; nt++) acc[nt] = (floatx4){0.f, 0.f, 0.f, 0.f};
#pragma unroll
        for (int ks = 0; ks < N1 / 32; ks++) {
            short8 av = *(const short8*)(a_base + ks * 32);
#pragma unroll
            for (int nt = 0; nt < NT; nt++) {
                short8 bv = *(const short8*)(b_base + nt * 16 * KP + ks * 32);
                acc[nt] = __builtin_amdgcn_mfma_f32_16x16x32_bf16(av, bv, acc[nt], 0, 0, 0);
            }
        }

        __syncthreads();   // Ws MFMA reads done -> overlay store scratch

#pragma unroll
        for (int nt = 0; nt < NT; nt++)
#pragma unroll
            for (int r = 0; r < 4; r++)
                sc[(lq * 4 + r) * CHP + nt * 16 + lm] = f2bf(acc[nt][r]);
        wave_lds_sync();

        constexpr int GPR = CH / 8;
#pragma unroll
        for (int it = 0; it < 2; it++) {
            int i = l + it * 64;
            int rr = i / GPR, cc = (i - rr * GPR) * 8;
            int gr = row0 + 16 * w + rr;
            if (gr < NN)
                *(uint4*)(g.C + (size_t)gr * Ntot2 + ch * CH + cc) = *(const uint4*)(sc + rr * CHP + cc);
        }
    }
}

// ======================= final: hmu=Amu@Wmu, hlv=Alv@Wlv, z=reparam(l2n(hmu),l2n(hlv)) ==========
__global__ __launch_bounds__(256) void final_gemm_k(const uint16_t* __restrict__ Amu,
                                                    const uint16_t* __restrict__ Alv,
                                                    const uint16_t* __restrict__ Wmu,
                                                    const uint16_t* __restrict__ Wlv,
                                                    float* __restrict__ out,
                                                    uint32_t k0, uint32_t k1)
{
    constexpr int K = 64, KP = K + 8, KC = K / 8, NT = 4;
    __shared__ uint16_t As[2][64 * KP];
    __shared__ uint16_t Ws[128 * KP];

    const int tid = threadIdx.x;
    const int row0 = blockIdx.x * 64;
    const int w  = tid >> 6;
    const int l  = tid & 63;
    const int lm = l & 15;
    const int lq = l >> 4;

    for (int i = tid; i < 64 * KC; i += 256) {
        int r = i / KC, c = i - r * KC;
        int gr = row0 + r; if (gr >= NN) gr = NN - 1;
        *(uint4*)(&As[0][r * KP + c * 8]) = *(const uint4*)(Amu + (size_t)gr * K + c * 8);
        *(uint4*)(&As[1][r * KP + c * 8]) = *(const uint4*)(Alv + (size_t)gr * K + c * 8);
    }
    for (int i = tid; i < 128 * KC; i += 256) {
        int r = i / KC, c = i - r * KC;
        uint4 v = (r < 64) ? *(const uint4*)(Wmu + (size_t)r * K + c * 8)
                           : *(const uint4*)(Wlv + (size_t)(r - 64) * K + c * 8);
        *(uint4*)(&Ws[r * KP + c * 8]) = v;
    }
    __syncthreads();

    const uint16_t* amu = &As[0][(16 * w + lm) * KP + lq * 8];
    const uint16_t* alv = &As[1][(16 * w + lm) * KP + lq * 8];
    const uint16_t* bmu = &Ws[lm * KP + lq * 8];
    const uint16_t* blv = &Ws[(64 + lm) * KP + lq * 8];

    floatx4 amu_acc[NT], alv_acc[NT];
#pragma unroll
    for (int nt = 0; nt < NT; nt++) {
        amu_acc[nt] = (floatx4){0.f, 0.f, 0.f, 0.f};
        alv_acc[nt] = (floatx4){0.f, 0.f, 0.f, 0.f};
    }
#pragma unroll
    for (int ks = 0; ks < K / 32; ks++) {
        short8 avm = *(const short8*)(amu + ks * 32);
        short8 avl = *(const short8*)(alv + ks * 32);
#pragma unroll
        for (int nt = 0; nt < NT; nt++) {
            short8 bvm = *(const short8*)(bmu + nt * 16 * KP + ks * 32);
            short8 bvl = *(const short8*)(blv + nt * 16 * KP + ks * 32);
            amu_acc[nt] = __builtin_amdgcn_mfma_f32_16x16x32_bf16(avm, bvm, amu_acc[nt], 0, 0, 0);
            alv_acc[nt] = __builtin_amdgcn_mfma_f32_16x16x32_bf16(avl, bvl, alv_acc[nt], 0, 0, 0);
        }
    }

    // row l2 norms (rows are wave-local: in-wave shuffle over the 16-lane column group)
    float smu[4] = {0.f, 0.f, 0.f, 0.f}, slv[4] = {0.f, 0.f, 0.f, 0.f};
#pragma unroll
    for (int nt = 0; nt < NT; nt++)
#pragma unroll
        for (int r = 0; r < 4; r++) {
            smu[r] = fmaf(amu_acc[nt][r], amu_acc[nt][r], smu[r]);
            slv[r] = fmaf(alv_acc[nt][r], alv_acc[nt][r], slv[r]);
        }
#pragma unroll
    for (int r = 0; r < 4; r++) {
#pragma unroll
        for (int m = 1; m <= 8; m <<= 1) {
            smu[r] += __shfl_xor(smu[r], m, 64);
            slv[r] += __shfl_xor(slv[r], m, 64);
        }
    }

    const float LO = -0.99999994f;
    const int grow = row0 + 16 * w + lq * 4;
#pragma unroll
    for (int r = 0; r < 4; r++) {
        const float dmu = fmaxf(sqrtf(smu[r]), 1e-12f);
        const float dlv = fmaxf(sqrtf(slv[r]), 1e-12f);
        const int gr = grow + r;
#pragma unroll
        for (int nt = 0; nt < NT; nt++) {
            float mu = amu_acc[nt][r] / dmu;
            float lv = alv_acc[nt][r] / dlv;
            uint32_t idx = (uint32_t)gr * 64u + (uint32_t)(nt * 16 + lm);
            float u01 = jax_u01(jax_bits32(k0, k1, idx));
            float u = fmaxf(LO, fmaf(u01, 2.0f, LO));
            float eps = 1.41421354f * erfinv_f(u);
            float stdv = expf(lv) + 1e-12f;
            if (gr < NN) out[idx] = fmaf(eps, stdv, mu);
        }
    }
}

// ======================= attention: 2 independent waves/block, 2-way batched =======================
struct AArg { const uint16_t* qkv; uint16_t* agg; };
struct AArgs2 { AArg a[2]; };

template<int DH>
__global__ __launch_bounds__(128) void attn_dual_k(AArgs2 as,
                                                   const int* __restrict__ rowptr,
                                                   const int* __restrict__ esrc,
                                                   float scale2, int str)
{
    constexpr int OD  = NH * DH;     // 128 / 64
    constexpr int QU  = DH / 8;      // uint4 loads per head slice (4 / 2)
    constexpr int CAP = 64;          // edges per chunk
    constexpr int NP  = CAP / 16;    // phase-1 passes (4)
    constexpr int FV  = OD / 16;     // dims per lane in phase 2 (8 / 4)
    constexpr int VW  = FV / 2;      // uint32 words per V slice (4 / 2)

    __shared__ float s_sc[2][CAP][4];
    __shared__ int   s_off[2][CAP];  // precomputed element offsets: src_node * str

    const uint16_t* qkv = as.a[blockIdx.y].qkv;
    uint16_t* agg       = as.a[blockIdx.y].agg;

    const int wv   = threadIdx.x >> 6;
    const int lane = threadIdx.x & 63;
    const int n    = blockIdx.x * 2 + wv;      // NN % 2 == 0
    const int h1   = lane & 3;
    const int e    = lane >> 2;
    const int g    = lane >> 4;
    const int dl   = lane & 15;
    const int h2   = dl >> 2;                  // head owning dims [dl*FV, dl*FV+FV)

    // q fragment kept PACKED (bf16x2 words) for v_dot2_f32_bf16
    uint32_t qw[DH / 2];
    {
        const uint4* q4 = (const uint4*)(qkv + (size_t)n * str + h1 * DH);
#pragma unroll
        for (int i = 0; i < QU; i++) {
            uint4 u = q4[i];
            qw[i * 4 + 0] = u.x; qw[i * 4 + 1] = u.y;
            qw[i * 4 + 2] = u.z; qw[i * 4 + 3] = u.w;
        }
    }

    const int j0 = rowptr[n], j1 = rowptr[n + 1];

    float m = -INFINITY, l = 0.0f;
    float acc[FV];
#pragma unroll
    for (int i = 0; i < FV; i++) acc[i] = 0.0f;

    const int voff = 2 * OD + dl * FV;

    for (int c0 = j0; c0 < j1; c0 += CAP) {
        const int cn = min(j1 - c0, CAP);

        if (lane < cn) s_off[wv][lane] = esrc[c0 + lane] * str;
        wave_lds_sync();

        // ---- V prefetch: first 16 edges, in flight concurrently with K gathers ----
        uint32_t vpre[4][VW];
#pragma unroll
        for (int t = 0; t < 4; t++) {
            const int j  = 4 * t + g;
            const int js = min(j, cn - 1);
            const uint16_t* vp = qkv + s_off[wv][js] + voff;
            if constexpr (VW == 4) {
                uint4 u = *(const uint4*)vp;
                vpre[t][0] = u.x; vpre[t][1] = u.y; vpre[t][2] = u.z; vpre[t][3] = u.w;
            } else {
                uint2 u = *(const uint2*)vp;
                vpre[t][0] = u.x; vpre[t][1] = u.y;
            }
        }

        // ---- phase 1: scores via packed bf16 dot2 ----
        float p[NP];
        float lm = -INFINITY;
#pragma unroll
        for (int t = 0; t < NP; t++) {
            const int j = e + 16 * t;
            float s = -INFINITY;
            if (j < cn) {
                const uint4* kp = (const uint4*)(qkv + s_off[wv][j] + OD + h1 * DH);
                float a0 = 0.0f, a1 = 0.0f;
#pragma unroll
                for (int i = 0; i < QU; i++) {
                    uint4 u = kp[i];
                    dot2bf(a0, qw[i * 4 + 0], u.x);
                    dot2bf(a1, qw[i * 4 + 1], u.y);
                    dot2bf(a0, qw[i * 4 + 2], u.z);
                    dot2bf(a1, qw[i * 4 + 3], u.w);
                }
                s = (a0 + a1) * scale2;
            }
            p[t] = s;
            lm = fmaxf(lm, s);
        }
#pragma unroll
        for (int msk = 4; msk <= 32; msk <<= 1) lm = fmaxf(lm, __shfl_xor(lm, msk, 64));
        const float mn = fmaxf(m, lm);
        const float corr = exp2f(m - mn);   // first chunk: exp2(-inf)=0 (acc already 0)
        m = mn;

        float ls = 0.0f;
#pragma unroll
        for (int t = 0; t < NP; t++) {
            const int j = e + 16 * t;
            float pe = 0.0f;
            if (j < cn) {
                pe = exp2f(p[t] - mn);
                s_sc[wv][j][h1] = pe;
            }
            ls += pe;
        }
#pragma unroll
        for (int msk = 4; msk <= 32; msk <<= 1) ls += __shfl_xor(ls, msk, 64);
        l = l * corr + ls;
        wave_lds_sync();

        // ---- phase 2: accumulate prefetched V (first 16 edges), then rare tail ----
        const float c2 = __shfl(corr, h2, 64);   // lane h2 has h1 == h2
#pragma unroll
        for (int i = 0; i < FV; i++) acc[i] *= c2;

#pragma unroll
        for (int t = 0; t < 4; t++) {
            const int j  = 4 * t + g;
            const int js = min(j, cn - 1);
            const float av = s_sc[wv][js][h2];
            const float alpha = (j < cn) ? av : 0.0f;
#pragma unroll
            for (int i = 0; i < VW; i++) {
                float lo, hi;
                unpk2(vpre[t][i], lo, hi);
                acc[2 * i + 0] = fmaf(alpha, lo, acc[2 * i + 0]);
                acc[2 * i + 1] = fmaf(alpha, hi, acc[2 * i + 1]);
            }
        }

        for (int jb = 16; jb < cn; jb += 4) {
            const int j = jb + g;
            if (j < cn) {
                const float alpha = s_sc[wv][j][h2];
                const uint16_t* vp = qkv + s_off[wv][j] + voff;
                if constexpr (FV == 8) {
                    uint4 u = *(const uint4*)vp;
                    float vf[8];
                    unpk8(u, vf);
#pragma unroll
                    for (int i = 0; i < 8; i++) acc[i] = fmaf(alpha, vf[i], acc[i]);
                } else {
                    uint2 u = *(const uint2*)vp;
                    float f0, f1, f2v, f3v;
                    unpk2(u.x, f0, f1);
                    unpk2(u.y, f2v, f3v);
                    acc[0] = fmaf(alpha, f0,  acc[0]);
                    acc[1] = fmaf(alpha, f1,  acc[1]);
                    acc[2] = fmaf(alpha, f2v, acc[2]);
                    acc[3] = fmaf(alpha, f3v, acc[3]);
                }
            }
        }
        wave_lds_sync();   // phase-2 LDS reads done before next chunk's s_off writes
    }

    // ---- epilogue: reduce over g, normalize, write ----
    const float lh = __shfl(l, h2, 64);
    const float inv = (lh > 0.0f) ? 1.0f / lh : 0.0f;
#pragma unroll
    for (int i = 0; i < FV; i++) {
        acc[i] += __shfl_xor(acc[i], 16, 64);
        acc[i] += __shfl_xor(acc[i], 32, 64);
    }
    if (g == 0) {
        uint16_t* op = agg + (size_t)n * OD + dl * FV;
        uint32_t wword[FV / 2];
#pragma unroll
        for (int i = 0; i < FV / 2; i++)
            wword[i] = (uint32_t)f2bf(acc[2 * i] * inv) | ((uint32_t)f2bf(acc[2 * i + 1] * inv) << 16);
        if constexpr (FV == 8) {
            *(uint4*)op = make_uint4(wword[0], wword[1], wword[2], wword[3]);
        } else {
            *(uint2*)op = make_uint2(wword[0], wword[1]);
        }
    }
}

// ======================= host side =======================
extern "C" void kernel_launch(void* const* d_in, const int* in_sizes, int n_in,
                              void* d_out, int out_size, void* d_ws, size_t ws_size,
                              hipStream_t stream)
{
    const float* feat    = (const float*)d_in[0];
    const int*   src     = (const int*)d_in[1];
    const int*   dst     = (const int*)d_in[2];
    const float* wqkv1_0 = (const float*)d_in[3];
    const float* wqkv1_r = (const float*)d_in[4];
    const float* wo1     = (const float*)d_in[5];
    const float* wqkv2_0 = (const float*)d_in[6];
    const float* wqkv2_r = (const float*)d_in[7];
    const float* wo2     = (const float*)d_in[8];
    const float* wqkv3_0 = (const float*)d_in[9];
    const float* wqkv3_r = (const float*)d_in[10];
    const float* wo3     = (const float*)d_in[11];
    float* out = (float*)d_out;

    char* wp = (char*)d_ws;
    auto alloc = [&](size_t bytes) { char* p = wp; wp += (bytes + 255) & ~(size_t)255; return p; };

    // ---- weight segments; gc2/gc3 qkv pairs adjacent for combined GEMMs ----
    WSegs segs;
    int offs[18];
    int acc_off = 0;
    auto seg = [&](int i, const float* p, int Bc, int Kc, int Cc) {
        segs.s[i].src = p; segs.s[i].B = Bc; segs.s[i].K = Kc; segs.s[i].C = Cc;
        segs.s[i].off = acc_off; offs[i] = acc_off; acc_off += Bc * Kc * Cc;
    };
    seg(0,  wqkv1_0,                 3, 256, 128);
    seg(1,  wqkv1_r,                 3, 128, 128);
    seg(2,  wqkv1_r + 3 * 128 * 128, 3, 128, 128);
    seg(3,  wo1,                     1, 128, 128);
    seg(4,  wo1 + 128 * 128,         1, 128, 128);
    seg(5,  wo1 + 2 * 128 * 128,     1, 128, 128);
    seg(6,  wqkv2_0,                 3, 128, 64);   // } contiguous 384 rows, K=128
    seg(7,  wqkv3_0,                 3, 128, 64);   // }
    seg(8,  wqkv2_r,                 3, 64, 64);
    seg(9,  wqkv3_r,                 3, 64, 64);
    seg(10, wqkv2_r + 3 * 64 * 64,   3, 64, 64);
    seg(11, wqkv3_r + 3 * 64 * 64,   3, 64, 64);
    seg(12, wo2,                     1, 64, 64);
    seg(13, wo2 + 64 * 64,           1, 64, 64);
    seg(14, wo2 + 2 * 64 * 64,       1, 64, 64);
    seg(15, wo3,                     1, 64, 64);
    seg(16, wo3 + 64 * 64,           1, 64, 64);
    seg(17, wo3 + 2 * 64 * 64,       1, 64, 64);

    uint16_t* Wt     = (uint16_t*)alloc((size_t)acc_off * 2);
    uint16_t* qkvL   = (uint16_t*)alloc((size_t)NN * 384 * 2);  // gc1 qkv / gc2+gc3 L1 combined
    uint16_t* agg128 = (uint16_t*)alloc((size_t)NN * 128 * 2);
    uint16_t* qkv_mu = (uint16_t*)alloc((size_t)NN * 192 * 2);
    uint16_t* qkv_lv = (uint16_t*)alloc((size_t)NN * 192 * 2);
    uint16_t* agg_mu = (uint16_t*)alloc((size_t)NN * 64 * 2);
    uint16_t* agg_lv = (uint16_t*)alloc((size_t)NN * 64 * 2);
    int* rowptr = (int*)alloc((size_t)(NN + 1) * 4);
    int* cursor = (int*)alloc((size_t)NN * 4);
    int* bsums  = (int*)alloc((size_t)SCAN_NBLK * 4);
    int* esrc   = (int*)alloc((size_t)NE * 4);

    wconv_k<<<dim3(384, 18), 256, 0, stream>>>(segs, Wt);

    fill_u32_k<<<(NN + 255) / 256, 256, 0, stream>>>((uint32_t*)cursor, 0u, NN);
    hist_k<<<(NE + 255) / 256, 256, 0, stream>>>(dst, cursor);
    scan1_k<<<SCAN_NBLK, 256, 0, stream>>>(cursor, rowptr, bsums);
    scan2_k<<<1, 64, 0, stream>>>(bsums);
    scan3_k<<<(NN + 255) / 256, 256, 0, stream>>>(rowptr, bsums, cursor);
    csr_scatter_k<<<(NE + 255) / 256, 256, 0, stream>>>(src, dst, cursor, esrc);

    uint32_t kd0, kd1, ke0, ke1;
    tf2x32(0u, 42u, 0u, 0u, kd0, kd1);
    tf2x32(0u, 42u, 0u, 1u, ke0, ke1);

    const int GX = (NN + 63) / 64;   // 782
    const float LOG2E = 1.4426950408889634f;
    const float sc32 = LOG2E / sqrtf(32.0f);
    const float sc16 = 0.25f * LOG2E;

    auto a1 = [&](AArg a) { AArgs2 r; r.a[0] = a; r.a[1] = a; return r; };
    auto a2 = [&](AArg a0, AArg b0) { AArgs2 r; r.a[0] = a0; r.a[1] = b0; return r; };
    auto f1 = [&](F2Arg a) { F2Args2 r; r.a[0] = a; r.a[1] = a; return r; };
    auto f2 = [&](F2Arg a0, F2Arg b0) { F2Args2 r; r.a[0] = a0; r.a[1] = b0; return r; };

    // LDS sizes
    const size_t L256_64 = (size_t)(64 + 64) * (256 + 8) * 2;   // 67584 (feat GEMM, CH=64)
    const size_t LF128   = (size_t)(64 + 64) * (128 + 8) * 2;   // 34816 (fused K=128, 2 regions)
    const size_t LF64    = (size_t)(64 + 64) * (64 + 8) * 2;    // 18432 (fused K=64, 2 regions)

    // ================= gc1 (od=128) =================
    // feat qkv GEMM: 3-way N-split (y = 128-col slice of the 384 outputs)
    GArg3 gf;
    for (int y = 0; y < 3; y++)
        gf.a[y] = GArg{feat, Wt + offs[0] + (size_t)y * 128 * 256, qkvL + y * 128};
    gemm_mfma_k<256, 64, true><<<dim3(GX, 3), 256, L256_64, stream>>>(gf, 384, 128, 0);
    attn_dual_k<32><<<dim3(NN / 2, 1), 128, 0, stream>>>(a1({qkvL, agg128}), rowptr, esrc, sc32, 384);

    // h = relu(agg@wo1_0); qkv = h@wqkv1_r0
    fused2_k<128, 0><<<dim3(GX, 1), 256, LF128, stream>>>(
        f1({agg128, Wt + offs[3], Wt + offs[1], qkvL}), 384, 0u, 0u);
    attn_dual_k<32><<<dim3(NN / 2, 1), 128, 0, stream>>>(a1({qkvL, agg128}), rowptr, esrc, sc32, 384);

    // h = relu(agg@wo1_1); qkv = h@wqkv1_r1
    fused2_k<128, 0><<<dim3(GX, 1), 256, LF128, stream>>>(
        f1({agg128, Wt + offs[4], Wt + offs[2], qkvL}), 384, 0u, 0u);
    attn_dual_k<32><<<dim3(NN / 2, 1), 128, 0, stream>>>(a1({qkvL, agg128}), rowptr, esrc, sc32, 384);

    // h = agg@wo1_2 (no relu); x = drop(relu(l2norm(h))); qkvL = x@[wqkv2_0|wqkv3_0]
    fused2_k<128, 1><<<dim3(GX, 1), 256, LF128, stream>>>(
        f1({agg128, Wt + offs[5], Wt + offs[6], qkvL}), 384, kd0, kd1);

    // ================= gc2 + gc3 batched (od=64) =================
    attn_dual_k<16><<<dim3(NN / 2, 2), 128, 0, stream>>>(
        a2({qkvL, agg_mu}, {qkvL + 192, agg_lv}), rowptr, esrc, sc16, 384);

    // h = relu(agg@wo_0); qkv = h@wqkv_r0  (mu | lv)
    fused2_k<64, 0><<<dim3(GX, 2), 256, LF64, stream>>>(
        f2({agg_mu, Wt + offs[12], Wt + offs[8],  qkv_mu},
           {agg_lv, Wt + offs[15], Wt + offs[9],  qkv_lv}), 192, 0u, 0u);
    attn_dual_k<16><<<dim3(NN / 2, 2), 128, 0, stream>>>(
        a2({qkv_mu, agg_mu}, {qkv_lv, agg_lv}), rowptr, esrc, sc16, 192);

    fused2_k<64, 0><<<dim3(GX, 2), 256, LF64, stream>>>(
        f2({agg_mu, Wt + offs[13], Wt + offs[10], qkv_mu},
           {agg_lv, Wt + offs[16], Wt + offs[11], qkv_lv}), 192, 0u, 0u);
    attn_dual_k<16><<<dim3(NN / 2, 2), 128, 0, stream>>>(
        a2({qkv_mu, agg_mu}, {qkv_lv, agg_lv}), rowptr, esrc, sc16, 192);

    // hmu = agg_mu@wo2_2, hlv = agg_lv@wo3_2, z = reparam(l2n(hmu), l2n(hlv))
    final_gemm_k<<<dim3(GX, 1), 256, 0, stream>>>(
        agg_mu, agg_lv, Wt + offs[14], Wt + offs[17], out, ke0, ke1);
}